// Round 4
// baseline (133.202 us; speedup 1.0000x reference)
//
#include <hip/hip_runtime.h>

// TargetAttention: scores = kv · q, softmax over heads (monotonic -> skip),
// argmax over 8 heads (first-occurrence), output winning 128-float row.
// B = 131072, H = 8, E = 128. Memory-bound: 576 MB read + 64 MB write.
//
// v3: explicit 2-stage software pipeline — next iteration's 5 loads are
// issued BEFORE the current iteration's shuffle-reduce + store, so VMEM
// stays busy during the ~1000-cycle serial DS chain. Two named register
// sets (no runtime-indexed arrays -> no scratch). __launch_bounds__(256,8)
// pins VGPR<=64 to keep 32 waves/CU.

constexpr int H = 8;
constexpr int E = 128;

typedef float f32x4 __attribute__((ext_vector_type(4)));

__global__ __launch_bounds__(256, 8) void TargetAttention_30142080483365_kernel(
    const float* __restrict__ q,   // [B, 1, E]
    const float* __restrict__ kv,  // [B, H, E]
    float* __restrict__ out,       // [B, E]
    int B, int total_waves) {
  const int tid  = blockIdx.x * blockDim.x + threadIdx.x;
  const int wave = tid >> 6;
  const int lane = threadIdx.x & 63;
  const int half = lane >> 5;   // head parity this lane's fragments belong to
  const int l32  = lane & 31;

  auto issue = [&](int bb, f32x4& qf, f32x4& k0, f32x4& k1, f32x4& k2,
                   f32x4& k3) {
    const f32x4* qv = reinterpret_cast<const f32x4*>(q + (size_t)bb * E);
    qf = __builtin_nontemporal_load(&qv[l32]);
    const f32x4* kvt =
        reinterpret_cast<const f32x4*>(kv + (size_t)bb * (H * E));
    k0 = __builtin_nontemporal_load(&kvt[0 * 64 + lane]);
    k1 = __builtin_nontemporal_load(&kvt[1 * 64 + lane]);
    k2 = __builtin_nontemporal_load(&kvt[2 * 64 + lane]);
    k3 = __builtin_nontemporal_load(&kvt[3 * 64 + lane]);
  };

  auto process = [&](int bb, const f32x4 qf, const f32x4 kf0, const f32x4 kf1,
                     const f32x4 kf2, const f32x4 kf3) {
    float s0 = kf0.x * qf.x + kf0.y * qf.y + kf0.z * qf.z + kf0.w * qf.w;
    float s1 = kf1.x * qf.x + kf1.y * qf.y + kf1.z * qf.z + kf1.w * qf.w;
    float s2 = kf2.x * qf.x + kf2.y * qf.y + kf2.z * qf.z + kf2.w * qf.w;
    float s3 = kf3.x * qf.x + kf3.y * qf.y + kf3.z * qf.z + kf3.w * qf.w;

    // Reduce-scatter: 4 partials/lane -> 1 partial/lane.
    const bool hi16 = (lane & 16) != 0;
    {
      float x = hi16 ? s0 : s2;
      float y = hi16 ? s1 : s3;
      float xr = __shfl_xor(x, 16, 64);
      float yr = __shfl_xor(y, 16, 64);
      s0 = (hi16 ? s2 : s0) + xr;
      s1 = (hi16 ? s3 : s1) + yr;
    }
    const bool hi8 = (lane & 8) != 0;
    float v;
    {
      float z = hi8 ? s0 : s1;
      float zr = __shfl_xor(z, 8, 64);
      v = (hi8 ? s1 : s0) + zr;
    }
    v += __shfl_xor(v, 4, 64);
    v += __shfl_xor(v, 2, 64);
    v += __shfl_xor(v, 1, 64);

    // head = 4*bit16 + 2*bit8 + half  (head <-> lane bits {5,4,3})
    int bh = 4 * (int)hi16 + 2 * (int)hi8 + half;
    float bs = v;

    // Argmax butterfly over lane bits 3,4,5; first-occurrence semantics.
#pragma unroll
    for (int m = 8; m <= 32; m <<= 1) {
      float os = __shfl_xor(bs, m, 64);
      int oh = __shfl_xor(bh, m, 64);
      if (os > bs || (os == bs && oh < bh)) { bs = os; bh = oh; }
    }

    // Write winning row from registers.
    const int fi = bh >> 1;
    f32x4 w01 = (fi & 1) ? kf1 : kf0;
    f32x4 w23 = (fi & 1) ? kf3 : kf2;
    f32x4 w = (fi & 2) ? w23 : w01;
    if (half == (bh & 1)) {
      f32x4* dst = reinterpret_cast<f32x4*>(out + (size_t)bb * E);
      __builtin_nontemporal_store(w, &dst[l32]);
    }
  };

  const int stride = total_waves;
  int b = wave;
  if (b >= B) return;

  f32x4 qfA, a0, a1, a2, a3;  // pipeline set A
  f32x4 qfB, c0, c1, c2, c3;  // pipeline set B

  issue(b, qfA, a0, a1, a2, a3);
  int bn = b + stride;
  while (bn < B) {
    // even slot: prefetch into B, process A
    issue(bn, qfB, c0, c1, c2, c3);
    process(b, qfA, a0, a1, a2, a3);
    b = bn;
    bn += stride;
    if (bn < B) {
      // odd slot: prefetch into A, process B
      issue(bn, qfA, a0, a1, a2, a3);
      process(b, qfB, c0, c1, c2, c3);
      b = bn;
      bn += stride;
    } else {
      process(b, qfB, c0, c1, c2, c3);
      return;
    }
  }
  process(b, qfA, a0, a1, a2, a3);
}

extern "C" void kernel_launch(void* const* d_in, const int* in_sizes, int n_in,
                              void* d_out, int out_size, void* d_ws, size_t ws_size,
                              hipStream_t stream) {
  const float* q  = (const float*)d_in[0];   // [B,1,E]
  const float* kv = (const float*)d_in[1];   // [B,H,E]
  float* out = (float*)d_out;                // [B,E]
  const int B = in_sizes[0] / E;             // 131072

  const int blocks = 2048;                   // 4 waves/block -> 8192 waves
  const int threads = 256;
  const int total_waves = blocks * (threads / 64);
  TargetAttention_30142080483365_kernel<<<blocks, threads, 0, stream>>>(
      q, kv, out, B, total_waves);
}

// Round 5
// 122.525 us; speedup vs baseline: 1.0871x; 1.0871x over previous
//
#include <hip/hip_runtime.h>

// TargetAttention: scores = kv · q, softmax over heads (monotonic -> skip),
// argmax over 8 heads (first-occurrence), output winning 128-float row.
// B = 131072, H = 8, E = 128. Memory-bound: 576 MB read + 64 MB write.
//
// v4: process an ADJACENT PAIR (b0, b1) per loop iteration, straight-line.
// 10 independent loads (8 KB kv + 2x512B q, all contiguous) are issued
// together before the two reduce chains -> 2x per-wave MLP vs v2b with no
// branchy pipeline, no occupancy pin (v3's mistake). Winning rows written
// from registers; non-temporal everywhere (zero reuse).

constexpr int H = 8;
constexpr int E = 128;

typedef float f32x4 __attribute__((ext_vector_type(4)));

__global__ __launch_bounds__(256) void TargetAttention_30142080483365_kernel(
    const float* __restrict__ q,   // [B, 1, E]
    const float* __restrict__ kv,  // [B, H, E]
    float* __restrict__ out,       // [B, E]
    int B, int total_waves) {
  const int tid  = blockIdx.x * blockDim.x + threadIdx.x;
  const int wave = tid >> 6;
  const int lane = threadIdx.x & 63;
  const int half = lane >> 5;   // head parity this lane's fragments belong to
  const int l32  = lane & 31;
  const bool hi16 = (lane & 16) != 0;
  const bool hi8  = (lane & 8) != 0;

  // Reduce 4 per-lane partials for one b, argmax, write winning row.
  auto process = [&](int bb, const f32x4 qf, const f32x4 kf0, const f32x4 kf1,
                     const f32x4 kf2, const f32x4 kf3) {
    float s0 = kf0.x * qf.x + kf0.y * qf.y + kf0.z * qf.z + kf0.w * qf.w;
    float s1 = kf1.x * qf.x + kf1.y * qf.y + kf1.z * qf.z + kf1.w * qf.w;
    float s2 = kf2.x * qf.x + kf2.y * qf.y + kf2.z * qf.z + kf2.w * qf.w;
    float s3 = kf3.x * qf.x + kf3.y * qf.y + kf3.z * qf.z + kf3.w * qf.w;

    // Reduce-scatter: 4 partials/lane -> 1 partial/lane.
    {
      float x = hi16 ? s0 : s2;
      float y = hi16 ? s1 : s3;
      float xr = __shfl_xor(x, 16, 64);
      float yr = __shfl_xor(y, 16, 64);
      s0 = (hi16 ? s2 : s0) + xr;
      s1 = (hi16 ? s3 : s1) + yr;
    }
    float v;
    {
      float z = hi8 ? s0 : s1;
      float zr = __shfl_xor(z, 8, 64);
      v = (hi8 ? s1 : s0) + zr;
    }
    v += __shfl_xor(v, 4, 64);
    v += __shfl_xor(v, 2, 64);
    v += __shfl_xor(v, 1, 64);

    // head = 4*bit16 + 2*bit8 + half  (head <-> lane bits {5,4,3})
    int bh = 4 * (int)hi16 + 2 * (int)hi8 + half;
    float bs = v;

    // Argmax butterfly over lane bits 3,4,5; first-occurrence semantics.
#pragma unroll
    for (int m = 8; m <= 32; m <<= 1) {
      float os = __shfl_xor(bs, m, 64);
      int oh = __shfl_xor(bh, m, 64);
      if (os > bs || (os == bs && oh < bh)) { bs = os; bh = oh; }
    }
    // (bs, bh) wave-uniform.

    // Write winning row from registers: row bh = fragment (bh>>1) of the
    // lanes whose half == (bh&1).
    const int fi = bh >> 1;
    f32x4 w01 = (fi & 1) ? kf1 : kf0;
    f32x4 w23 = (fi & 1) ? kf3 : kf2;
    f32x4 w = (fi & 2) ? w23 : w01;
    if (half == (bh & 1)) {
      f32x4* dst = reinterpret_cast<f32x4*>(out + (size_t)bb * E);
      __builtin_nontemporal_store(w, &dst[l32]);
    }
  };

  const int nPairs = B >> 1;
  for (int p = wave; p < nPairs; p += total_waves) {
    const int b0 = 2 * p;
    const int b1 = b0 + 1;

    // q fragments for both rows (512 B each, contiguous).
    const f32x4* qv0 = reinterpret_cast<const f32x4*>(q + (size_t)b0 * E);
    const f32x4* qv1 = reinterpret_cast<const f32x4*>(q + (size_t)b1 * E);
    const f32x4 qf0 = __builtin_nontemporal_load(&qv0[l32]);
    const f32x4 qf1 = __builtin_nontemporal_load(&qv1[l32]);

    // Pair kv tile: 2048 floats = 512 float4 = 8 KB contiguous -> 8 loads.
    // float4 index j*64+lane: j=0..3 -> b0 heads {half,2+half,4+half,6+half},
    // j=4..7 -> b1 same pattern; row elements 4*l32 .. 4*l32+3.
    const f32x4* kvt = reinterpret_cast<const f32x4*>(kv + (size_t)b0 * (H * E));
    const f32x4 k0 = __builtin_nontemporal_load(&kvt[0 * 64 + lane]);
    const f32x4 k1 = __builtin_nontemporal_load(&kvt[1 * 64 + lane]);
    const f32x4 k2 = __builtin_nontemporal_load(&kvt[2 * 64 + lane]);
    const f32x4 k3 = __builtin_nontemporal_load(&kvt[3 * 64 + lane]);
    const f32x4 k4 = __builtin_nontemporal_load(&kvt[4 * 64 + lane]);
    const f32x4 k5 = __builtin_nontemporal_load(&kvt[5 * 64 + lane]);
    const f32x4 k6 = __builtin_nontemporal_load(&kvt[6 * 64 + lane]);
    const f32x4 k7 = __builtin_nontemporal_load(&kvt[7 * 64 + lane]);

    process(b0, qf0, k0, k1, k2, k3);
    process(b1, qf1, k4, k5, k6, k7);
  }
}

extern "C" void kernel_launch(void* const* d_in, const int* in_sizes, int n_in,
                              void* d_out, int out_size, void* d_ws, size_t ws_size,
                              hipStream_t stream) {
  const float* q  = (const float*)d_in[0];   // [B,1,E]
  const float* kv = (const float*)d_in[1];   // [B,H,E]
  float* out = (float*)d_out;                // [B,E]
  const int B = in_sizes[0] / E;             // 131072

  const int blocks = 2048;                   // 4 waves/block -> 8192 waves
  const int threads = 256;
  const int total_waves = blocks * (threads / 64);
  TargetAttention_30142080483365_kernel<<<blocks, threads, 0, stream>>>(
      q, kv, out, B, total_waves);
}